// Round 3
// baseline (290.425 us; speedup 1.0000x reference)
//
#include <hip/hip_runtime.h>
#include <cstdint>
#include <cstddef>

typedef __bf16 bf16;
typedef __bf16 bf16x8 __attribute__((ext_vector_type(8)));
typedef __bf16 bf16x4 __attribute__((ext_vector_type(4)));
typedef short  s16x4  __attribute__((ext_vector_type(4)));
typedef float  f32x4  __attribute__((ext_vector_type(4)));

#define MFMA16(a, b, c) __builtin_amdgcn_mfma_f32_16x16x32_bf16((a), (b), (c), 0, 0, 0)

#if __has_builtin(__builtin_amdgcn_mfma_f32_16x16x16bf16_1k)
#define HAVE_K16 1
#else
#define HAVE_K16 0
#endif

#if __has_builtin(__builtin_amdgcn_exp2f)
#define EXP2(x) __builtin_amdgcn_exp2f(x)
#else
#define EXP2(x) exp2f(x)
#endif

// Problem constants
constexpr int Bsz = 4;
constexpr int T   = 2048;
constexpr int Cd  = 1024;
constexpr int Hn  = 16;
constexpr int Mrows = Bsz * T;          // 8192
constexpr int QKV_LD = 3 * Cd;          // 3072

// softmax scale folded into Q at GEMM1 epilogue: 1/sqrt(64) * log2(e)
constexpr float QSCALE = 0.125f * 1.4426950408889634f;

// ---------------------------------------------------------------------------
// fp32 -> bf16 elementwise convert (8 elems / thread)
// ---------------------------------------------------------------------------
__global__ __launch_bounds__(256) void cvt_f32_bf16(const float* __restrict__ in,
                                                    bf16* __restrict__ out, int n) {
    int i = (blockIdx.x * 256 + threadIdx.x) * 8;
    if (i >= n) return;
    float4 a = *(const float4*)(in + i);
    float4 b = *(const float4*)(in + i + 4);
    bf16x8 o;
    o[0] = (bf16)a.x; o[1] = (bf16)a.y; o[2] = (bf16)a.z; o[3] = (bf16)a.w;
    o[4] = (bf16)b.x; o[5] = (bf16)b.y; o[6] = (bf16)b.z; o[7] = (bf16)b.w;
    *(bf16x8*)(out + i) = o;
}

// ---------------------------------------------------------------------------
// W [KDIM][NDIM] fp32 -> Wt [NDIM][KDIM] bf16 (tiled transpose)
// ---------------------------------------------------------------------------
template <int KDIM, int NDIM>
__global__ __launch_bounds__(256) void transpose_cvt(const float* __restrict__ W,
                                                     bf16* __restrict__ Wt) {
    __shared__ float tile[32][33];
    int k0 = blockIdx.y * 32;
    int n0 = blockIdx.x * 32;
    int tx = threadIdx.x;   // 0..31
    int ty = threadIdx.y;   // 0..7
    #pragma unroll
    for (int r = 0; r < 32; r += 8)
        tile[r + ty][tx] = W[(size_t)(k0 + r + ty) * NDIM + n0 + tx];
    __syncthreads();
    #pragma unroll
    for (int r = 0; r < 32; r += 8)
        Wt[(size_t)(n0 + r + ty) * KDIM + k0 + tx] = (bf16)tile[tx][r + ty];
}

// ---------------------------------------------------------------------------
// 256x256-tile 8-wave 8-phase bf16 GEMM (m201-style template, self-derived
// schedule):  out[M][N] = A[M][K] * Bt[N][K]^T + bias,  K = 1024.
//
//  - 512 threads = 8 waves (2 M-waves x 4 N-waves); per-wave 128x64 output
//    = 8x4 fragments of 16x16; acc = 128 VGPR.
//  - LDS 128 KiB: A[2 dbuf][2 half][128 slot][64 k] + B same. K-tile kt
//    lives in dbuf kt&1. A-half h = row bit6 (slot = (row>>7)*64 + row&63),
//    B-half h = col bit5 (slot = (col>>6)*32 + col&31) — exactly the rows/
//    cols one quadrant-phase consumes, so halves free up mid-tile.
//  - granule-XOR swizzle (g ^= slot&7) on both the pre-swizzled global
//    source k and the ds_read granule -> conflict-free ds_read_b128
//    (same swizzle as the verified 128^2 kernel).
//  - 8 phases/iter, 2 K-tiles/iter; each phase: 12 ds_read_b128 + 1
//    half-tile stage (2 global_load_lds dwordx4) + s_barrier + 16 MFMA
//    (setprio-wrapped) + s_waitcnt vmcnt(6) lgkmcnt(0) + s_barrier.
//    vmcnt(6) (never 0 in the loop) keeps 3 half-tiles in flight; audited:
//    it retires exactly the halves the next phase reads, incl. prologue.
//    Raw s_barrier (NOT __syncthreads) avoids the vmcnt(0) drain.
//  - stage(kt>=KT) no-op handles the tail iteration.
// ---------------------------------------------------------------------------
template <int N, bool OUT_BF16>
__global__ __launch_bounds__(512, 2) void gemm256(const bf16* __restrict__ A,
                                                  const bf16* __restrict__ Bt,
                                                  const float* __restrict__ bias,
                                                  void* __restrict__ outp,
                                                  float oscale, int oscale_n) {
    constexpr int K  = 1024;
    constexpr int KT = K / 64;          // 16 K-tiles
    __shared__ __align__(16) bf16 lds[65536];   // A: [0,32768), B: [32768,65536)

    const int tid  = threadIdx.x;
    const int wv   = tid >> 6;          // 0..7
    const int lane = tid & 63;
    const int wm   = wv >> 2;           // 0..1 : M-wave
    const int wn   = wv & 3;            // 0..3 : N-wave
    const int quad = lane >> 4, c16 = lane & 15;
    const int sw   = c16 & 7;

    // XCD-aware bijective remap: 8 m-tiles spread mod 8 across XCDs.
    // grid = (M/256)*(N/256) = 32*(N/256); requires grid % 32 == 0.
    const int lin = (int)blockIdx.x;
    const int x8  = lin & 7;
    const int q   = lin >> 3;
    const int m0  = (x8 + 8 * (q & 3)) * 256;
    const int n0  = (q >> 2) * 256;

    // Stage one half-tile (128 slots x 64 k = 16 KB) of K-tile kt.
    // Per wave: 2 rounds x 1 global_load_lds (64 lanes x 16 B = 1 KB each).
    // LDS content at [slot][g] = source granule g ^ (slot&7).
    auto stage = [&](int kt, int isB, int h, int db) {
        if (kt >= KT) return;
        #pragma unroll
        for (int r = 0; r < 2; ++r) {
            const int idx  = r * 512 + tid;
            const int slot = idx >> 3;
            const int gq   = idx & 7;
            const int kg   = kt * 64 + ((gq ^ (slot & 7)) << 3);
            const bf16* src;
            if (isB) {
                const int col = ((slot >> 5) << 6) + h * 32 + (slot & 31);
                src = Bt + (size_t)(n0 + col) * K + kg;
            } else {
                const int row = ((slot >> 6) << 7) + h * 64 + (slot & 63);
                src = A + (size_t)(m0 + row) * K + kg;
            }
            bf16* dst = &lds[(isB ? 32768 : 0) + db * 16384 + h * 8192 + (r * 8 + wv) * 512];
            __builtin_amdgcn_global_load_lds(
                (const __attribute__((address_space(1))) void*)src,
                (__attribute__((address_space(3))) void*)dst, 16, 0, 0);
        }
    };

    f32x4 acc[8][4] = {};

#define PHASE(QM, QN, DB, SKT, SISB, SH, SDB)                                    \
    {                                                                            \
        bf16x8 af[4][2], bfr[2][2];                                              \
        _Pragma("unroll") for (int mq = 0; mq < 4; ++mq)                         \
            _Pragma("unroll") for (int ks = 0; ks < 2; ++ks)                     \
                af[mq][ks] = *(const bf16x8*)&lds[(DB) * 16384 + (QM) * 8192 +   \
                    (wm * 64 + mq * 16 + c16) * 64 + (((ks * 4 + quad) ^ sw) << 3)]; \
        _Pragma("unroll") for (int nq = 0; nq < 2; ++nq)                         \
            _Pragma("unroll") for (int ks = 0; ks < 2; ++ks)                     \
                bfr[nq][ks] = *(const bf16x8*)&lds[32768 + (DB) * 16384 + (QN) * 8192 + \
                    (wn * 32 + nq * 16 + c16) * 64 + (((ks * 4 + quad) ^ sw) << 3)]; \
        stage((SKT), (SISB), (SH), (SDB));                                       \
        __builtin_amdgcn_s_barrier();                                            \
        __builtin_amdgcn_s_setprio(1);                                           \
        _Pragma("unroll") for (int mq = 0; mq < 4; ++mq)                         \
            _Pragma("unroll") for (int nq = 0; nq < 2; ++nq)                     \
                _Pragma("unroll") for (int ks = 0; ks < 2; ++ks)                 \
                    acc[(QM) * 4 + mq][(QN) * 2 + nq] =                          \
                        MFMA16(af[mq][ks], bfr[nq][ks],                          \
                               acc[(QM) * 4 + mq][(QN) * 2 + nq]);               \
        __builtin_amdgcn_s_setprio(0);                                           \
        asm volatile("s_waitcnt vmcnt(6) lgkmcnt(0)" ::: "memory");              \
        __builtin_amdgcn_s_barrier();                                            \
    }

    // Prologue: tile 0 complete (db0) + tile 1 B-half0 (db1); drain tile 0.
    stage(0, 0, 0, 0);
    stage(0, 1, 0, 0);
    stage(0, 0, 1, 0);
    stage(0, 1, 1, 0);
    stage(1, 1, 0, 1);
    asm volatile("s_waitcnt vmcnt(2)" ::: "memory");
    __builtin_amdgcn_s_barrier();

    for (int it = 0; it < KT / 2; ++it) {
        const int v  = 2 * it + 1;
        const int u2 = 2 * it + 2;
        const int v2 = 2 * it + 3;
        PHASE(0, 0, 0,  v, 0, 0, 1)     // compute u h0xh0 | stage v.A0
        PHASE(1, 0, 0,  v, 0, 1, 1)     //         u h1xh0 | stage v.A1
        PHASE(0, 1, 0,  v, 1, 1, 1)     //         u h0xh1 | stage v.B1
        PHASE(1, 1, 0, u2, 1, 0, 0)     //         u h1xh1 | stage u2.B0
        PHASE(0, 0, 1, u2, 0, 0, 0)     //         v h0xh0 | stage u2.A0
        PHASE(1, 0, 1, u2, 0, 1, 0)     //         v h1xh0 | stage u2.A1
        PHASE(0, 1, 1, u2, 1, 1, 0)     //         v h0xh1 | stage u2.B1
        PHASE(1, 1, 1, v2, 1, 0, 1)     //         v h1xh1 | stage v2.B0
    }
#undef PHASE

    #pragma unroll
    for (int nb = 0; nb < 4; ++nb) {
        const int n = n0 + wn * 64 + nb * 16 + c16;
        const float bv = bias[n];
        const float sc = (n < oscale_n) ? oscale : 1.0f;
        #pragma unroll
        for (int mb = 0; mb < 8; ++mb) {
            const int mbase = m0 + wm * 128 + mb * 16 + quad * 4;
            #pragma unroll
            for (int r = 0; r < 4; ++r) {
                float val = (acc[mb][nb][r] + bv) * sc;
                if (OUT_BF16)
                    ((bf16*)outp)[(size_t)(mbase + r) * N + n] = (bf16)val;
                else
                    ((float*)outp)[(size_t)(mbase + r) * N + n] = val;
            }
        }
    }
}

// ---------------------------------------------------------------------------
// Flash-style causal attention, v9 (unchanged from round 2 for attribution):
// split-K flash-decoding (3-way), two-phase CU-uniform fold, S^T=K*Q^T
// register-resident P, Vs granule-XOR swizzle, unnormalized bf16 partials.
// ---------------------------------------------------------------------------
__global__ __launch_bounds__(256, 2) void attn_fwd(const bf16* __restrict__ qkv,
                                                   bf16* __restrict__ yp0,
                                                   bf16* __restrict__ yp1,
                                                   bf16* __restrict__ yp2,
                                                   float* __restrict__ lp) {
    __shared__ __align__(16) bf16 Ks2[2][4096];       // [buf][512*key8 + 64*dgrp + 8*k7 + d7]
    __shared__ __align__(16) bf16 Vs[2][64 * 64];     // [buf] V^T [d][key], granule-XOR swizzled
#if !HAVE_K16
    __shared__ __align__(16) bf16 Ps[4][32 * 72];     // fallback: [wave][q][key]
#endif

    const int x    = blockIdx.x;                      // 0..23
    const int xq   = x / 3;                           // 0..7 : q-tile pair index
    const int sgl  = x - 3 * xq;                      // 0..2 : key segment
    const int h    = blockIdx.y;
    const int bb   = blockIdx.z;
    const int tid  = threadIdx.x;
    const int w    = tid >> 6;
    const int lane = tid & 63;
    const int quad = lane >> 4, c16 = lane & 15;

    const size_t base = (size_t)(bb * T) * QKV_LD;

    const int g = tid >> 5;   // 0..7  : d-group for V staging
    const int p = tid & 31;   // 0..31 : key-pair for V staging

    auto vs_store = [&](bf16* vbuf, const bf16x8& va, const bf16x8& vb) {
        #pragma unroll
        for (int j = 0; j < 8; ++j) {
            union { bf16 hh[2]; uint32_t u; } pk;
            pk.hh[0] = va[j]; pk.hh[1] = vb[j];
            const int row = 8 * g + j;
            *(uint32_t*)&vbuf[row * 64 + (((p >> 1) ^ (row & 15)) << 2) + ((p & 1) << 1)] = pk.u;
        }
    };

    bf16* __restrict__ ydst = (sgl == 0) ? yp0 : ((sgl == 1) ? yp1 : yp2);
    float* __restrict__ ldst = lp + (size_t)sgl * Mrows * Hn;

    for (int ph = 0; ph < 2; ++ph) {
        const int qt = ph ? xq : (15 - xq);           // phase 0: heavy tile
        const int q0 = qt * 128;
        const int rowbase = q0 + w * 32;

        const int n = 2 * qt + 2;
        int f0, f1;
        if (ph == 0) { f0 = (n + 2) / 3; f1 = (n + 1) / 3; }
        else         { f0 = n / 3;       f1 = (n + 1) / 3; }
        const int start = (sgl == 0) ? 0 : ((sgl == 1) ? f0 : f0 + f1);
        const int nkt   = (sgl == 0) ? f0 : ((sgl == 1) ? f1 : n - f0 - f1);

        __syncthreads();

        {
            const int kb = start * 64;
            #pragma unroll
            for (int ii = 0; ii < 2; ++ii) {
                const int i = 2 * w + ii;
                const bf16* gp = qkv + base + (size_t)(kb + 8 * i + (lane & 7)) * QKV_LD + Cd + h * 64 + (lane >> 3) * 8;
                __builtin_amdgcn_global_load_lds(
                    (const __attribute__((address_space(1))) void*)gp,
                    (__attribute__((address_space(3))) void*)(&Ks2[0][i * 512]), 16, 0, 0);
            }
            const bf16* vp = qkv + base + (size_t)(kb + 2 * p) * QKV_LD + 2 * Cd + h * 64 + g * 8;
            bf16x8 va = *(const bf16x8*)vp;
            bf16x8 vb = *(const bf16x8*)(vp + QKV_LD);
            vs_store(Vs[0], va, vb);
        }

        bf16x8 qf[2][2];
        #pragma unroll
        for (int mb = 0; mb < 2; ++mb) {
            const bf16* qp = qkv + base + (size_t)(rowbase + 16 * mb + c16) * QKV_LD + h * 64 + quad * 8;
            qf[mb][0] = *(const bf16x8*)qp;
            qf[mb][1] = *(const bf16x8*)(qp + 32);
        }

        f32x4 yacc[2][4] = {};
        float lsum[2] = {};

        for (int j = 0; j < nkt; ++j) {
            const int cur = j & 1, nxt = cur ^ 1;
            const int k0 = (start + j) * 64;
            __syncthreads();

            bf16x8 va, vb;
            const bool more = (j + 1 < nkt);
            if (more) {
                const int kn = k0 + 64;
                #pragma unroll
                for (int ii = 0; ii < 2; ++ii) {
                    const int i = 2 * w + ii;
                    const bf16* gp = qkv + base + (size_t)(kn + 8 * i + (lane & 7)) * QKV_LD + Cd + h * 64 + (lane >> 3) * 8;
                    __builtin_amdgcn_global_load_lds(
                        (const __attribute__((address_space(1))) void*)gp,
                        (__attribute__((address_space(3))) void*)(&Ks2[nxt][i * 512]), 16, 0, 0);
                }
                const bf16* vp = qkv + base + (size_t)(kn + 2 * p) * QKV_LD + 2 * Cd + h * 64 + g * 8;
                va = *(const bf16x8*)vp;
                vb = *(const bf16x8*)(vp + QKV_LD);
            }

            if (k0 <= rowbase + 31) {
                f32x4 s[2][4] = {};
                #pragma unroll
                for (int ks = 0; ks < 2; ++ks)
                    #pragma unroll
                    for (int blk = 0; blk < 4; ++blk) {
                        const bf16x8 kf = *(const bf16x8*)
                            &Ks2[cur][(2 * blk + (c16 >> 3)) * 512 + (4 * ks + quad) * 64 + (c16 & 7) * 8];
                        #pragma unroll
                        for (int mb = 0; mb < 2; ++mb)
                            s[mb][blk] = MFMA16(kf, qf[mb][ks], s[mb][blk]);
                    }

#if HAVE_K16
                union B4 { bf16x4 v; s16x4 s; } pb[2][4];
#endif
                #pragma unroll
                for (int mb = 0; mb < 2; ++mb) {
                    const int rb = rowbase + 16 * mb;
                    const int qglob = rb + c16;
                    const bool needMask = (k0 + 63 > rb);
                    #pragma unroll
                    for (int blk = 0; blk < 4; ++blk) {
                        #pragma unroll
                        for (int r = 0; r < 4; ++r) {
                            const int key = k0 + blk * 16 + quad * 4 + r;
                            float e = s[mb][blk][r];
                            if (needMask) e = (key > qglob) ? -INFINITY : e;
                            float pv = EXP2(e);
                            lsum[mb] += pv;
#if HAVE_K16
                            pb[mb][blk].v[r] = (bf16)pv;
#else
                            Ps[w][(mb * 16 + c16) * 72 + blk * 16 + quad * 4 + r] = (bf16)pv;
#endif
                        }
                    }
                }

#if HAVE_K16
                #pragma unroll
                for (int blk = 0; blk < 4; ++blk)
                    #pragma unroll
                    for (int d16 = 0; d16 < 4; ++d16) {
                        union B4u { bf16x4 v; s16x4 s; } vf;
                        vf.v = *(const bf16x4*)
                            &Vs[cur][(d16 * 16 + c16) * 64 + ((((blk << 2) | quad) ^ c16) << 2)];
                        #pragma unroll
                        for (int mb = 0; mb < 2; ++mb)
                            yacc[mb][d16] = __builtin_amdgcn_mfma_f32_16x16x16bf16_1k(
                                vf.s, pb[mb][blk].s, yacc[mb][d16], 0, 0, 0);
                    }
#else
                asm volatile("s_waitcnt lgkmcnt(0)" ::: "memory");
                #pragma unroll
                for (int ks = 0; ks < 2; ++ks) {
                    bf16x8 pf0 = *(const bf16x8*)&Ps[w][(0 * 16 + c16) * 72 + ks * 32 + quad * 8];
                    bf16x8 pf1 = *(const bf16x8*)&Ps[w][(1 * 16 + c16) * 72 + ks * 32 + quad * 8];
                    #pragma unroll
                    for (int d16 = 0; d16 < 4; ++d16) {
                        const int row = d16 * 16 + c16;
                        const int g0 = ks * 8 + quad * 2;
                        bf16x4 lo = *(const bf16x4*)&Vs[cur][row * 64 + ((g0 ^ c16) << 2)];
                        bf16x4 hi = *(const bf16x4*)&Vs[cur][row * 64 + (((g0 + 1) ^ c16) << 2)];
                        bf16x8 vfr;
                        vfr[0] = lo[0]; vfr[1] = lo[1]; vfr[2] = lo[2]; vfr[3] = lo[3];
                        vfr[4] = hi[0]; vfr[5] = hi[1]; vfr[6] = hi[2]; vfr[7] = hi[3];
                        yacc[0][d16] = MFMA16(pf0, vfr, yacc[0][d16]);
                        yacc[1][d16] = MFMA16(pf1, vfr, yacc[1][d16]);
                    }
                }
#endif
            }

            if (more)
                vs_store(Vs[nxt], va, vb);
        }

        #pragma unroll
        for (int mb = 0; mb < 2; ++mb) {
            lsum[mb] += __shfl_xor(lsum[mb], 16);
            lsum[mb] += __shfl_xor(lsum[mb], 32);
        }

#if HAVE_K16
        #pragma unroll
        for (int mb = 0; mb < 2; ++mb) {
            const int row = rowbase + 16 * mb + c16;
            bf16* yw = ydst + (size_t)(bb * T + row) * Cd + h * 64;
            #pragma unroll
            for (int d16 = 0; d16 < 4; ++d16) {
                bf16x4 o;
                #pragma unroll
                for (int r = 0; r < 4; ++r)
                    o[r] = (bf16)(yacc[mb][d16][r]);
                *(bf16x4*)(yw + d16 * 16 + quad * 4) = o;
            }
            if (quad == 0)
                ldst[(size_t)(bb * T + row) * Hn + h] = lsum[mb];
        }
#else
        #pragma unroll
        for (int mb = 0; mb < 2; ++mb)
            #pragma unroll
            for (int r = 0; r < 4; ++r) {
                const float lsv = __shfl(lsum[mb], quad * 4 + r);
                const int row = rowbase + 16 * mb + quad * 4 + r;
                bf16* yw = ydst + (size_t)(bb * T + row) * Cd + h * 64;
                #pragma unroll
                for (int d16 = 0; d16 < 4; ++d16)
                    yw[d16 * 16 + c16] = (bf16)(yacc[mb][d16][r]);
                if (c16 == 0)
                    ldst[(size_t)(bb * T + row) * Hn + h] = lsv;
            }
#endif
    }
}

// ---------------------------------------------------------------------------
// Combine split-K partials: y = (y0 + y1 + y2) / (l0 + l1 + l2).
// ---------------------------------------------------------------------------
__global__ __launch_bounds__(256) void attn_combine(const bf16* __restrict__ yp0,
                                                    const bf16* __restrict__ yp1,
                                                    const bf16* __restrict__ yp2,
                                                    const float* __restrict__ lp,
                                                    bf16* __restrict__ y) {
    int i = (blockIdx.x * 256 + threadIdx.x) * 8;
    int row = i >> 10;          // / Cd
    int hh  = (i & 1023) >> 6;  // head
    const size_t S = (size_t)Mrows * Hn;
    const size_t li = (size_t)row * Hn + hh;
    float l = lp[li] + lp[S + li] + lp[2 * S + li];
    float inv = 1.f / l;
    bf16x8 a = *(const bf16x8*)(yp0 + i);
    bf16x8 b = *(const bf16x8*)(yp1 + i);
    bf16x8 c = *(const bf16x8*)(yp2 + i);
    bf16x8 o;
    #pragma unroll
    for (int j = 0; j < 8; ++j)
        o[j] = (bf16)(((float)a[j] + (float)b[j] + (float)c[j]) * inv);
    *(bf16x8*)(y + i) = o;
}

// ---------------------------------------------------------------------------
extern "C" void kernel_launch(void* const* d_in, const int* in_sizes, int n_in,
                              void* d_out, int out_size, void* d_ws, size_t ws_size,
                              hipStream_t stream) {
    const float* x      = (const float*)d_in[0];
    const float* W_attn = (const float*)d_in[1];
    const float* b_attn = (const float*)d_in[2];
    const float* W_proj = (const float*)d_in[3];
    const float* b_proj = (const float*)d_in[4];
    float* out = (float*)d_out;

    bf16* xb   = (bf16*)d_ws;                               // 16.8 MB (yp2 after gemm1)
    bf16* Wat  = xb  + (size_t)Mrows * Cd;                  // 6.3 MB  (lp after gemm1)
    bf16* Wpt  = Wat + (size_t)QKV_LD * Cd;                 // 2.1 MB
    bf16* qkv  = Wpt + (size_t)Cd * Cd;                     // 50.3 MB
    bf16* yb   = qkv + (size_t)Mrows * QKV_LD;              // 16.8 MB (yp0 + combined)
    bf16* yp1  = yb  + (size_t)Mrows * Cd;                  // 16.8 MB
    bf16*  yp2 = xb;                                        // 3rd split-K partial
    float* lp  = (float*)Wat;                               // 3 x Mrows x Hn = 1.57 MB

    cvt_f32_bf16<<<(Mrows * Cd) / (256 * 8), 256, 0, stream>>>(x, xb, Mrows * Cd);
    transpose_cvt<Cd, QKV_LD><<<dim3(QKV_LD / 32, Cd / 32), dim3(32, 8), 0, stream>>>(W_attn, Wat);
    transpose_cvt<Cd, Cd><<<dim3(Cd / 32, Cd / 32), dim3(32, 8), 0, stream>>>(W_proj, Wpt);

    // Q columns (n < 1024) pre-scaled by 1/sqrt(D)*log2e for the attn exp2
    gemm256<QKV_LD, true><<<dim3((Mrows / 256) * (QKV_LD / 256)), dim3(512), 0, stream>>>(
        xb, Wat, b_attn, qkv, QSCALE, Cd);

    attn_fwd<<<dim3(24, Hn, Bsz), 256, 0, stream>>>(qkv, yb, yp1, yp2, lp);
    attn_combine<<<(Mrows * Cd) / (256 * 8), 256, 0, stream>>>(yb, yp1, yp2, lp, yb);

    gemm256<Cd, false><<<dim3((Mrows / 256) * (Cd / 256)), dim3(512), 0, stream>>>(
        yb, Wpt, b_proj, out, 1.0f, 0);
}

// Round 4
// 272.003 us; speedup vs baseline: 1.0677x; 1.0677x over previous
//
#include <hip/hip_runtime.h>
#include <cstdint>
#include <cstddef>

typedef __bf16 bf16;
typedef __bf16 bf16x8 __attribute__((ext_vector_type(8)));
typedef __bf16 bf16x4 __attribute__((ext_vector_type(4)));
typedef short  s16x4  __attribute__((ext_vector_type(4)));
typedef float  f32x4  __attribute__((ext_vector_type(4)));

#define MFMA16(a, b, c) __builtin_amdgcn_mfma_f32_16x16x32_bf16((a), (b), (c), 0, 0, 0)

#if __has_builtin(__builtin_amdgcn_mfma_f32_16x16x16bf16_1k)
#define HAVE_K16 1
#else
#define HAVE_K16 0
#endif

#if __has_builtin(__builtin_amdgcn_exp2f)
#define EXP2(x) __builtin_amdgcn_exp2f(x)
#else
#define EXP2(x) exp2f(x)
#endif

// Problem constants
constexpr int Bsz = 4;
constexpr int T   = 2048;
constexpr int Cd  = 1024;
constexpr int Hn  = 16;
constexpr int Mrows = Bsz * T;          // 8192
constexpr int QKV_LD = 3 * Cd;          // 3072

// softmax scale folded into Q at GEMM1 epilogue: 1/sqrt(64) * log2(e)
constexpr float QSCALE = 0.125f * 1.4426950408889634f;

// ---------------------------------------------------------------------------
// fp32 -> bf16 elementwise convert (8 elems / thread)
// ---------------------------------------------------------------------------
__global__ __launch_bounds__(256) void cvt_f32_bf16(const float* __restrict__ in,
                                                    bf16* __restrict__ out, int n) {
    int i = (blockIdx.x * 256 + threadIdx.x) * 8;
    if (i >= n) return;
    float4 a = *(const float4*)(in + i);
    float4 b = *(const float4*)(in + i + 4);
    bf16x8 o;
    o[0] = (bf16)a.x; o[1] = (bf16)a.y; o[2] = (bf16)a.z; o[3] = (bf16)a.w;
    o[4] = (bf16)b.x; o[5] = (bf16)b.y; o[6] = (bf16)b.z; o[7] = (bf16)b.w;
    *(bf16x8*)(out + i) = o;
}

// ---------------------------------------------------------------------------
// W [KDIM][NDIM] fp32 -> Wt [NDIM][KDIM] bf16 (tiled transpose)
// ---------------------------------------------------------------------------
template <int KDIM, int NDIM>
__global__ __launch_bounds__(256) void transpose_cvt(const float* __restrict__ W,
                                                     bf16* __restrict__ Wt) {
    __shared__ float tile[32][33];
    int k0 = blockIdx.y * 32;
    int n0 = blockIdx.x * 32;
    int tx = threadIdx.x;   // 0..31
    int ty = threadIdx.y;   // 0..7
    #pragma unroll
    for (int r = 0; r < 32; r += 8)
        tile[r + ty][tx] = W[(size_t)(k0 + r + ty) * NDIM + n0 + tx];
    __syncthreads();
    #pragma unroll
    for (int r = 0; r < 32; r += 8)
        Wt[(size_t)(n0 + r + ty) * KDIM + k0 + tx] = (bf16)tile[tx][r + ty];
}

// ---------------------------------------------------------------------------
// 256x256-tile 8-wave bf16 GEMM, v2 of the deep-pipelined schedule.
// Round-3 defects fixed:
//  (a) fragment reuse: 24 ds_read_b128 / K-tile (was 48). Phase order
//      (0,0),(0,1),(1,0),(1,1); A-half registers reused across two phases,
//      BOTH B quadrant-sets register-resident for the whole K-tile.
//  (b) reads hit db = kt&1, stage-writes hit db^1 -> no pre-MFMA barrier
//      needed; 4 barriers/K-tile (was 8).
//  (c) stage tile u+1 during tile u: A0+B0@P1, B1@P2, A1@P3. FIFO-audited
//      waits: vmcnt(6)@P1, vmcnt(6)@P2, none@P3, vmcnt(4)@P4 -> every half
//      retires >=1 barrier before first read, ~3.5-phase in-flight (~HBM
//      latency). Tail tile 15: vmcnt(2)/vmcnt(0).
// granule-XOR swizzle as verified: LDS[slot][g] holds global granule
// g ^ (slot&7); reads XOR with sw = c16&7 -> conflict-free b128.
// ---------------------------------------------------------------------------
template <int N, bool OUT_BF16>
__global__ __launch_bounds__(512, 2) void gemm256(const bf16* __restrict__ A,
                                                  const bf16* __restrict__ Bt,
                                                  const float* __restrict__ bias,
                                                  void* __restrict__ outp,
                                                  float oscale, int oscale_n) {
    constexpr int K  = 1024;
    constexpr int KT = K / 64;          // 16 K-tiles
    __shared__ __align__(16) bf16 lds[65536];   // A: [0,32768), B: [32768,65536)

    const int tid  = threadIdx.x;
    const int wv   = tid >> 6;          // 0..7
    const int lane = tid & 63;
    const int wm   = wv >> 2;           // 0..1 : M-wave
    const int wn   = wv & 3;            // 0..3 : N-wave
    const int quad = lane >> 4, c16 = lane & 15;
    const int sw   = c16 & 7;

    // XCD-aware bijective remap (requires 32 M-tiles: Mrows/256 == 32)
    const int lin = (int)blockIdx.x;
    const int x8  = lin & 7;
    const int q   = lin >> 3;
    const int m0  = (x8 + 8 * (q & 3)) * 256;
    const int n0  = (q >> 2) * 256;

    // Stage one 16KB half-tile (A-half or B-half) of K-tile kt into db=kt&1.
    // 2 global_load_lds per wave (4 rounds x 512 threads x 16 B).
    auto stage = [&](int kt, int isB, int h) {
        if (kt >= KT) return;
        const int db = kt & 1;
        #pragma unroll
        for (int r = 0; r < 2; ++r) {
            const int idx  = r * 512 + tid;
            const int slot = idx >> 3;
            const int gq   = idx & 7;
            const int kg   = kt * 64 + ((gq ^ (slot & 7)) << 3);
            const bf16* src;
            if (isB) {
                const int col = ((slot >> 5) << 6) + h * 32 + (slot & 31);
                src = Bt + (size_t)(n0 + col) * K + kg;
            } else {
                const int row = ((slot >> 6) << 7) + h * 64 + (slot & 63);
                src = A + (size_t)(m0 + row) * K + kg;
            }
            bf16* dst = &lds[(isB ? 32768 : 0) + db * 16384 + h * 8192 + (r * 8 + wv) * 512];
            __builtin_amdgcn_global_load_lds(
                (const __attribute__((address_space(1))) void*)src,
                (__attribute__((address_space(3))) void*)dst, 16, 0, 0);
        }
    };

    f32x4 acc[8][4] = {};
    bf16x8 af[4][2], b0[2][2], b1[2][2];

#define READ_A(QM, DB)                                                           \
    _Pragma("unroll") for (int mq = 0; mq < 4; ++mq)                             \
        _Pragma("unroll") for (int ks = 0; ks < 2; ++ks)                         \
            af[mq][ks] = *(const bf16x8*)&lds[(DB) * 16384 + (QM) * 8192 +       \
                (wm * 64 + mq * 16 + c16) * 64 + (((ks * 4 + quad) ^ sw) << 3)];
#define READ_B(DST, QN, DB)                                                      \
    _Pragma("unroll") for (int nq = 0; nq < 2; ++nq)                             \
        _Pragma("unroll") for (int ks = 0; ks < 2; ++ks)                         \
            DST[nq][ks] = *(const bf16x8*)&lds[32768 + (DB) * 16384 + (QN) * 8192 + \
                (wn * 32 + nq * 16 + c16) * 64 + (((ks * 4 + quad) ^ sw) << 3)];
#define MFMA_Q(QM, QN, BREG)                                                     \
    __builtin_amdgcn_s_setprio(1);                                               \
    _Pragma("unroll") for (int mq = 0; mq < 4; ++mq)                             \
        _Pragma("unroll") for (int nq = 0; nq < 2; ++nq)                         \
            _Pragma("unroll") for (int ks = 0; ks < 2; ++ks)                     \
                acc[(QM) * 4 + mq][(QN) * 2 + nq] =                              \
                    MFMA16(af[mq][ks], BREG[nq][ks],                             \
                           acc[(QM) * 4 + mq][(QN) * 2 + nq]);                   \
    __builtin_amdgcn_s_setprio(0);
#define VMBAR(NSTR)                                                              \
    asm volatile("s_waitcnt vmcnt(" NSTR ")" ::: "memory");                      \
    __builtin_amdgcn_s_barrier();

    // Prologue: tile 0 complete into db0 (A0,B0,B1,A1); wait for A0,B0.
    stage(0, 0, 0); stage(0, 1, 0); stage(0, 1, 1); stage(0, 0, 1);
    VMBAR("4")

    #pragma unroll 1
    for (int u = 0; u < KT - 1; ++u) {
        const int db = u & 1;
        const int kn = u + 1;
        // P1: compute quadrant (0,0); stage (u+1).A0, (u+1).B0
        READ_A(0, db)
        READ_B(b0, 0, db)
        stage(kn, 0, 0); stage(kn, 1, 0);
        MFMA_Q(0, 0, b0)
        VMBAR("6")
        // P2: quadrant (0,1); stage (u+1).B1
        READ_B(b1, 1, db)
        stage(kn, 1, 1);
        MFMA_Q(0, 1, b1)
        VMBAR("6")
        // P3: quadrant (1,0); stage (u+1).A1
        READ_A(1, db)
        stage(kn, 0, 1);
        MFMA_Q(1, 0, b0)
        __builtin_amdgcn_s_barrier();
        // P4: quadrant (1,1); register-only
        MFMA_Q(1, 1, b1)
        VMBAR("4")
    }

    // Tail: tile 15 (db1), no staging; drain waits.
    READ_A(0, 1)
    READ_B(b0, 0, 1)
    MFMA_Q(0, 0, b0)
    VMBAR("2")
    READ_B(b1, 1, 1)
    MFMA_Q(0, 1, b1)
    VMBAR("0")
    READ_A(1, 1)
    MFMA_Q(1, 0, b0)
    MFMA_Q(1, 1, b1)

#undef READ_A
#undef READ_B
#undef MFMA_Q
#undef VMBAR

    #pragma unroll
    for (int nb = 0; nb < 4; ++nb) {
        const int n = n0 + wn * 64 + nb * 16 + c16;
        const float bv = bias[n];
        const float sc = (n < oscale_n) ? oscale : 1.0f;
        #pragma unroll
        for (int mb = 0; mb < 8; ++mb) {
            const int mbase = m0 + wm * 128 + mb * 16 + quad * 4;
            #pragma unroll
            for (int r = 0; r < 4; ++r) {
                float val = (acc[mb][nb][r] + bv) * sc;
                if (OUT_BF16)
                    ((bf16*)outp)[(size_t)(mbase + r) * N + n] = (bf16)val;
                else
                    ((float*)outp)[(size_t)(mbase + r) * N + n] = val;
            }
        }
    }
}

// ---------------------------------------------------------------------------
// bf16 MFMA GEMM, 128^2 (m97 pattern) — kept for GEMM2 (N=1024: 512-block
// grid beats a 128-block 256^2 grid). Granule-XOR swizzle + XCD remap.
// ---------------------------------------------------------------------------
template <int N, bool OUT_BF16>
__global__ __launch_bounds__(256) void gemm_bf16(const bf16* __restrict__ A,
                                                 const bf16* __restrict__ Bt,
                                                 const float* __restrict__ bias,
                                                 void* __restrict__ outp,
                                                 float oscale, int oscale_n) {
    constexpr int K = 1024;
    __shared__ __align__(16) bf16 As[128 * 64];
    __shared__ __align__(16) bf16 Bs[128 * 64];

    const int tid  = threadIdx.x;
    const int w    = tid >> 6;
    const int lane = tid & 63;
    const int wm   = w & 1, wn = w >> 1;
    const int quad = lane >> 4, c16 = lane & 15;

    const int lin = (int)(blockIdx.y * gridDim.x + blockIdx.x);
    const int x8  = lin & 7;
    const int q   = lin >> 3;
    const int m0  = (x8 + 8 * (q & 7)) * 128;
    const int n0  = (q >> 3) * 128;

    const int srow = lane >> 3;                      // 0..7
    const int scol = ((lane & 7) ^ srow) * 8;        // swizzled source granule
    const int sw   = c16 & 7;                        // fragment-read swizzle key

    f32x4 acc[4][4] = {};

    for (int kt = 0; kt < K / 64; ++kt) {
        const int kk = kt * 64;
        #pragma unroll
        for (int i = 0; i < 4; ++i) {
            const int arow = 32 * w + 8 * i;
            __builtin_amdgcn_global_load_lds(
                (const __attribute__((address_space(1))) void*)(A + (size_t)(m0 + arow + srow) * K + kk + scol),
                (__attribute__((address_space(3))) void*)(&As[arow * 64]),
                16, 0, 0);
            __builtin_amdgcn_global_load_lds(
                (const __attribute__((address_space(1))) void*)(Bt + (size_t)(n0 + arow + srow) * K + kk + scol),
                (__attribute__((address_space(3))) void*)(&Bs[arow * 64]),
                16, 0, 0);
        }
        __syncthreads();

        #pragma unroll
        for (int ks = 0; ks < 2; ++ks) {
            const int go = ((ks * 4 + quad) ^ sw) * 8;   // swizzled granule offset
            bf16x8 af[4], bfv[4];
            #pragma unroll
            for (int mb = 0; mb < 4; ++mb)
                af[mb] = *(const bf16x8*)&As[(wm * 64 + mb * 16 + c16) * 64 + go];
            #pragma unroll
            for (int nb = 0; nb < 4; ++nb)
                bfv[nb] = *(const bf16x8*)&Bs[(wn * 64 + nb * 16 + c16) * 64 + go];
            #pragma unroll
            for (int mb = 0; mb < 4; ++mb)
                #pragma unroll
                for (int nb = 0; nb < 4; ++nb)
                    acc[mb][nb] = MFMA16(af[mb], bfv[nb], acc[mb][nb]);
        }
        __syncthreads();
    }

    #pragma unroll
    for (int nb = 0; nb < 4; ++nb) {
        const int n = n0 + wn * 64 + nb * 16 + c16;
        const float bv = bias[n];
        const float sc = (n < oscale_n) ? oscale : 1.0f;
        #pragma unroll
        for (int mb = 0; mb < 4; ++mb) {
            const int mbase = m0 + wm * 64 + mb * 16 + quad * 4;
            #pragma unroll
            for (int r = 0; r < 4; ++r) {
                float v = (acc[mb][nb][r] + bv) * sc;
                if (OUT_BF16)
                    ((bf16*)outp)[(size_t)(mbase + r) * N + n] = (bf16)v;
                else
                    ((float*)outp)[(size_t)(mbase + r) * N + n] = v;
            }
        }
    }
}

// ---------------------------------------------------------------------------
// Flash-style causal attention, v9 (unchanged for attribution):
// split-K flash-decoding (3-way), two-phase CU-uniform fold, S^T=K*Q^T
// register-resident P, Vs granule-XOR swizzle, unnormalized bf16 partials.
// ---------------------------------------------------------------------------
__global__ __launch_bounds__(256, 2) void attn_fwd(const bf16* __restrict__ qkv,
                                                   bf16* __restrict__ yp0,
                                                   bf16* __restrict__ yp1,
                                                   bf16* __restrict__ yp2,
                                                   float* __restrict__ lp) {
    __shared__ __align__(16) bf16 Ks2[2][4096];       // [buf][512*key8 + 64*dgrp + 8*k7 + d7]
    __shared__ __align__(16) bf16 Vs[2][64 * 64];     // [buf] V^T [d][key], granule-XOR swizzled
#if !HAVE_K16
    __shared__ __align__(16) bf16 Ps[4][32 * 72];     // fallback: [wave][q][key]
#endif

    const int x    = blockIdx.x;                      // 0..23
    const int xq   = x / 3;                           // 0..7 : q-tile pair index
    const int sgl  = x - 3 * xq;                      // 0..2 : key segment
    const int h    = blockIdx.y;
    const int bb   = blockIdx.z;
    const int tid  = threadIdx.x;
    const int w    = tid >> 6;
    const int lane = tid & 63;
    const int quad = lane >> 4, c16 = lane & 15;

    const size_t base = (size_t)(bb * T) * QKV_LD;

    const int g = tid >> 5;   // 0..7  : d-group for V staging
    const int p = tid & 31;   // 0..31 : key-pair for V staging

    auto vs_store = [&](bf16* vbuf, const bf16x8& va, const bf16x8& vb) {
        #pragma unroll
        for (int j = 0; j < 8; ++j) {
            union { bf16 hh[2]; uint32_t u; } pk;
            pk.hh[0] = va[j]; pk.hh[1] = vb[j];
            const int row = 8 * g + j;
            *(uint32_t*)&vbuf[row * 64 + (((p >> 1) ^ (row & 15)) << 2) + ((p & 1) << 1)] = pk.u;
        }
    };

    bf16* __restrict__ ydst = (sgl == 0) ? yp0 : ((sgl == 1) ? yp1 : yp2);
    float* __restrict__ ldst = lp + (size_t)sgl * Mrows * Hn;

    for (int ph = 0; ph < 2; ++ph) {
        const int qt = ph ? xq : (15 - xq);           // phase 0: heavy tile
        const int q0 = qt * 128;
        const int rowbase = q0 + w * 32;

        const int n = 2 * qt + 2;
        int f0, f1;
        if (ph == 0) { f0 = (n + 2) / 3; f1 = (n + 1) / 3; }
        else         { f0 = n / 3;       f1 = (n + 1) / 3; }
        const int start = (sgl == 0) ? 0 : ((sgl == 1) ? f0 : f0 + f1);
        const int nkt   = (sgl == 0) ? f0 : ((sgl == 1) ? f1 : n - f0 - f1);

        __syncthreads();

        {
            const int kb = start * 64;
            #pragma unroll
            for (int ii = 0; ii < 2; ++ii) {
                const int i = 2 * w + ii;
                const bf16* gp = qkv + base + (size_t)(kb + 8 * i + (lane & 7)) * QKV_LD + Cd + h * 64 + (lane >> 3) * 8;
                __builtin_amdgcn_global_load_lds(
                    (const __attribute__((address_space(1))) void*)gp,
                    (__attribute__((address_space(3))) void*)(&Ks2[0][i * 512]), 16, 0, 0);
            }
            const bf16* vp = qkv + base + (size_t)(kb + 2 * p) * QKV_LD + 2 * Cd + h * 64 + g * 8;
            bf16x8 va = *(const bf16x8*)vp;
            bf16x8 vb = *(const bf16x8*)(vp + QKV_LD);
            vs_store(Vs[0], va, vb);
        }

        bf16x8 qf[2][2];
        #pragma unroll
        for (int mb = 0; mb < 2; ++mb) {
            const bf16* qp = qkv + base + (size_t)(rowbase + 16 * mb + c16) * QKV_LD + h * 64 + quad * 8;
            qf[mb][0] = *(const bf16x8*)qp;
            qf[mb][1] = *(const bf16x8*)(qp + 32);
        }

        f32x4 yacc[2][4] = {};
        float lsum[2] = {};

        for (int j = 0; j < nkt; ++j) {
            const int cur = j & 1, nxt = cur ^ 1;
            const int k0 = (start + j) * 64;
            __syncthreads();

            bf16x8 va, vb;
            const bool more = (j + 1 < nkt);
            if (more) {
                const int kn = k0 + 64;
                #pragma unroll
                for (int ii = 0; ii < 2; ++ii) {
                    const int i = 2 * w + ii;
                    const bf16* gp = qkv + base + (size_t)(kn + 8 * i + (lane & 7)) * QKV_LD + Cd + h * 64 + (lane >> 3) * 8;
                    __builtin_amdgcn_global_load_lds(
                        (const __attribute__((address_space(1))) void*)gp,
                        (__attribute__((address_space(3))) void*)(&Ks2[nxt][i * 512]), 16, 0, 0);
                }
                const bf16* vp = qkv + base + (size_t)(kn + 2 * p) * QKV_LD + 2 * Cd + h * 64 + g * 8;
                va = *(const bf16x8*)vp;
                vb = *(const bf16x8*)(vp + QKV_LD);
            }

            if (k0 <= rowbase + 31) {
                f32x4 s[2][4] = {};
                #pragma unroll
                for (int ks = 0; ks < 2; ++ks)
                    #pragma unroll
                    for (int blk = 0; blk < 4; ++blk) {
                        const bf16x8 kf = *(const bf16x8*)
                            &Ks2[cur][(2 * blk + (c16 >> 3)) * 512 + (4 * ks + quad) * 64 + (c16 & 7) * 8];
                        #pragma unroll
                        for (int mb = 0; mb < 2; ++mb)
                            s[mb][blk] = MFMA16(kf, qf[mb][ks], s[mb][blk]);
                    }

#if HAVE_K16
                union B4 { bf16x4 v; s16x4 s; } pb[2][4];
#endif
                #pragma unroll
                for (int mb = 0; mb < 2; ++mb) {
                    const int rb = rowbase + 16 * mb;
                    const int qglob = rb + c16;
                    const bool needMask = (k0 + 63 > rb);
                    #pragma unroll
                    for (int blk = 0; blk < 4; ++blk) {
                        #pragma unroll
                        for (int r = 0; r < 4; ++r) {
                            const int key = k0 + blk * 16 + quad * 4 + r;
                            float e = s[mb][blk][r];
                            if (needMask) e = (key > qglob) ? -INFINITY : e;
                            float pv = EXP2(e);
                            lsum[mb] += pv;
#if HAVE_K16
                            pb[mb][blk].v[r] = (bf16)pv;
#else
                            Ps[w][(mb * 16 + c16) * 72 + blk * 16 + quad * 4 + r] = (bf16)pv;
#endif
                        }
                    }
                }

#if HAVE_K16
                #pragma unroll
                for (int blk = 0; blk < 4; ++blk)
                    #pragma unroll
                    for (int d16 = 0; d16 < 4; ++d16) {
                        union B4u { bf16x4 v; s16x4 s; } vf;
                        vf.v = *(const bf16x4*)
                            &Vs[cur][(d16 * 16 + c16) * 64 + ((((blk << 2) | quad) ^ c16) << 2)];
                        #pragma unroll
                        for (int mb = 0; mb < 2; ++mb)
                            yacc[mb][d16] = __builtin_amdgcn_mfma_f32_16x16x16bf16_1k(
                                vf.s, pb[mb][blk].s, yacc[mb][d16], 0, 0, 0);
                    }
#else
                asm volatile("s_waitcnt lgkmcnt(0)" ::: "memory");
                #pragma unroll
                for (int ks = 0; ks < 2; ++ks) {
                    bf16x8 pf0 = *(const bf16x8*)&Ps[w][(0 * 16 + c16) * 72 + ks * 32 + quad * 8];
                    bf16x8 pf1 = *(const bf16x8*)&Ps[w][(1 * 16 + c16) * 72 + ks * 32 + quad * 8];
                    #pragma unroll
                    for (int d16 = 0; d16 < 4; ++d16) {
                        const int row = d16 * 16 + c16;
                        const int g0 = ks * 8 + quad * 2;
                        bf16x4 lo = *(const bf16x4*)&Vs[cur][row * 64 + ((g0 ^ c16) << 2)];
                        bf16x4 hi = *(const bf16x4*)&Vs[cur][row * 64 + (((g0 + 1) ^ c16) << 2)];
                        bf16x8 vfr;
                        vfr[0] = lo[0]; vfr[1] = lo[1]; vfr[2] = lo[2]; vfr[3] = lo[3];
                        vfr[4] = hi[0]; vfr[5] = hi[1]; vfr[6] = hi[2]; vfr[7] = hi[3];
                        yacc[0][d16] = MFMA16(pf0, vfr, yacc[0][d16]);
                        yacc[1][d16] = MFMA16(pf1, vfr, yacc[1][d16]);
                    }
                }
#endif
            }

            if (more)
                vs_store(Vs[nxt], va, vb);
        }

        #pragma unroll
        for (int mb = 0; mb < 2; ++mb) {
            lsum[mb] += __shfl_xor(lsum[mb], 16);
            lsum[mb] += __shfl_xor(lsum[mb], 32);
        }

#if HAVE_K16
        #pragma unroll
        for (int mb = 0; mb < 2; ++mb) {
            const int row = rowbase + 16 * mb + c16;
            bf16* yw = ydst + (size_t)(bb * T + row) * Cd + h * 64;
            #pragma unroll
            for (int d16 = 0; d16 < 4; ++d16) {
                bf16x4 o;
                #pragma unroll
                for (int r = 0; r < 4; ++r)
                    o[r] = (bf16)(yacc[mb][d16][r]);
                *(bf16x4*)(yw + d16 * 16 + quad * 4) = o;
            }
            if (quad == 0)
                ldst[(size_t)(bb * T + row) * Hn + h] = lsum[mb];
        }
#else
        #pragma unroll
        for (int mb = 0; mb < 2; ++mb)
            #pragma unroll
            for (int r = 0; r < 4; ++r) {
                const float lsv = __shfl(lsum[mb], quad * 4 + r);
                const int row = rowbase + 16 * mb + quad * 4 + r;
                bf16* yw = ydst + (size_t)(bb * T + row) * Cd + h * 64;
                #pragma unroll
                for (int d16 = 0; d16 < 4; ++d16)
                    yw[d16 * 16 + c16] = (bf16)(yacc[mb][d16][r]);
                if (c16 == 0)
                    ldst[(size_t)(bb * T + row) * Hn + h] = lsv;
            }
#endif
    }
}

// ---------------------------------------------------------------------------
// Combine split-K partials: y = (y0 + y1 + y2) / (l0 + l1 + l2).
// ---------------------------------------------------------------------------
__global__ __launch_bounds__(256) void attn_combine(const bf16* __restrict__ yp0,
                                                    const bf16* __restrict__ yp1,
                                                    const bf16* __restrict__ yp2,
                                                    const float* __restrict__ lp,
                                                    bf16* __restrict__ y) {
    int i = (blockIdx.x * 256 + threadIdx.x) * 8;
    int row = i >> 10;          // / Cd
    int hh  = (i & 1023) >> 6;  // head
    const size_t S = (size_t)Mrows * Hn;
    const size_t li = (size_t)row * Hn + hh;
    float l = lp[li] + lp[S + li] + lp[2 * S + li];
    float inv = 1.f / l;
    bf16x8 a = *(const bf16x8*)(yp0 + i);
    bf16x8 b = *(const bf16x8*)(yp1 + i);
    bf16x8 c = *(const bf16x8*)(yp2 + i);
    bf16x8 o;
    #pragma unroll
    for (int j = 0; j < 8; ++j)
        o[j] = (bf16)(((float)a[j] + (float)b[j] + (float)c[j]) * inv);
    *(bf16x8*)(y + i) = o;
}

// ---------------------------------------------------------------------------
extern "C" void kernel_launch(void* const* d_in, const int* in_sizes, int n_in,
                              void* d_out, int out_size, void* d_ws, size_t ws_size,
                              hipStream_t stream) {
    const float* x      = (const float*)d_in[0];
    const float* W_attn = (const float*)d_in[1];
    const float* b_attn = (const float*)d_in[2];
    const float* W_proj = (const float*)d_in[3];
    const float* b_proj = (const float*)d_in[4];
    float* out = (float*)d_out;

    bf16* xb   = (bf16*)d_ws;                               // 16.8 MB (yp2 after gemm1)
    bf16* Wat  = xb  + (size_t)Mrows * Cd;                  // 6.3 MB  (lp after gemm1)
    bf16* Wpt  = Wat + (size_t)QKV_LD * Cd;                 // 2.1 MB
    bf16* qkv  = Wpt + (size_t)Cd * Cd;                     // 50.3 MB
    bf16* yb   = qkv + (size_t)Mrows * QKV_LD;              // 16.8 MB (yp0 + combined)
    bf16* yp1  = yb  + (size_t)Mrows * Cd;                  // 16.8 MB
    bf16*  yp2 = xb;                                        // 3rd split-K partial
    float* lp  = (float*)Wat;                               // 3 x Mrows x Hn = 1.57 MB

    cvt_f32_bf16<<<(Mrows * Cd) / (256 * 8), 256, 0, stream>>>(x, xb, Mrows * Cd);
    transpose_cvt<Cd, QKV_LD><<<dim3(QKV_LD / 32, Cd / 32), dim3(32, 8), 0, stream>>>(W_attn, Wat);
    transpose_cvt<Cd, Cd><<<dim3(Cd / 32, Cd / 32), dim3(32, 8), 0, stream>>>(W_proj, Wpt);

    // Q columns (n < 1024) pre-scaled by 1/sqrt(D)*log2e for the attn exp2
    gemm256<QKV_LD, true><<<dim3((Mrows / 256) * (QKV_LD / 256)), dim3(512), 0, stream>>>(
        xb, Wat, b_attn, qkv, QSCALE, Cd);

    attn_fwd<<<dim3(24, Hn, Bsz), 256, 0, stream>>>(qkv, yb, yp1, yp2, lp);
    attn_combine<<<(Mrows * Cd) / (256 * 8), 256, 0, stream>>>(yb, yp1, yp2, lp, yb);

    gemm_bf16<Cd, false><<<dim3(Cd / 128, Mrows / 128), 256, 0, stream>>>(
        yb, Wpt, b_proj, out, 1.0f, 0);
}